// Round 1
// baseline (1276.724 us; speedup 1.0000x reference)
//
#include <hip/hip_runtime.h>
#include <hip/hip_bf16.h>
#include <stdint.h>

#define M_DIM 4096
#define K_DIM 4096
#define N_DIM 11008
#define BK 64
#define NT (K_DIM / BK)   // 64 K-steps

typedef __bf16 bf16_t;
typedef __bf16 bf16x8 __attribute__((ext_vector_type(8)));
typedef float floatx4 __attribute__((ext_vector_type(4)));

// ---------------------------------------------------------------------------
// k_prescale: xs[m, perm(k)] = bf16(x[m,k] * s[k/64]);
//             crow[m] = sum_k float(xs) * (zp[g] + 136)
// k-permutation within each aligned 8-group: slots (0,2,4,6,1,3,5,7) ->
// matches the register-unpacked B fragment order in k_gemm (lo nibbles
// first). Dot products are invariant since A and B use the same order.
// +136 folds the w-magic offset (GEMM feeds w4+136 to the MFMA).
// ---------------------------------------------------------------------------
__global__ __launch_bounds__(256) void k_prescale(
    const float* __restrict__ x,
    const float* __restrict__ scales,
    const float* __restrict__ zps,
    bf16_t* __restrict__ xs,
    float* __restrict__ crow)
{
    const int m = blockIdx.x;
    const int t = threadIdx.x;
    const float4* xr = (const float4*)(x + (size_t)m * K_DIM);
    bf16x8* xo = (bf16x8*)(xs + (size_t)m * K_DIM);
    float acc = 0.f;
#pragma unroll
    for (int i = 0; i < 2; ++i) {
        const int idx = i * 256 + t;          // 8-elem group index (512/row)
        const int g = idx >> 3;               // 64 elems per quant group
        const float s = scales[g];
        const float tz = zps[g] + 136.0f;
        const float4 v0 = xr[2 * idx];
        const float4 v1 = xr[2 * idx + 1];
        bf16x8 o;
        o[0] = (bf16_t)(v0.x * s);  // k+0
        o[1] = (bf16_t)(v0.z * s);  // k+2
        o[2] = (bf16_t)(v1.x * s);  // k+4
        o[3] = (bf16_t)(v1.z * s);  // k+6
        o[4] = (bf16_t)(v0.y * s);  // k+1
        o[5] = (bf16_t)(v0.w * s);  // k+3
        o[6] = (bf16_t)(v1.y * s);  // k+5
        o[7] = (bf16_t)(v1.w * s);  // k+7
        xo[idx] = o;
        float ssum = 0.f;
#pragma unroll
        for (int j = 0; j < 8; ++j) ssum += (float)o[j];
        acc += ssum * tz;
    }
#pragma unroll
    for (int off = 32; off > 0; off >>= 1) acc += __shfl_down(acc, off, 64);
    __shared__ float wsum[4];
    const int wave = t >> 6, lane = t & 63;
    if (lane == 0) wsum[wave] = acc;
    __syncthreads();
    if (t == 0) crow[m] = wsum[0] + wsum[1] + wsum[2] + wsum[3];
}

// ---------------------------------------------------------------------------
// k_gemm, fused int4 decode, B kept entirely in registers.
//   out[m,n] = sum_k xs[m,k]*(w4[n,k]+136) + bias[n] - crow[m]
// Block tile 256x128, BK=64, 4 waves in 2(m)x2(n): wave tile 128x64.
//
// NEW vs previous version: T3+T4 software pipeline.
//  - A double-buffered in LDS (2 x 32 KB). DMAs for tile kt+1 are issued at
//    the TOP of iteration kt; compute runs on the other buffer.
//  - counted s_waitcnt vmcnt(8) at iteration end (drains the 8 A-DMAs, keeps
//    the 8 B prefetch loads in flight) + raw s_barrier (no compiler drain —
//    __syncthreads would emit vmcnt(0) and serialize everything).
//  - A-fragment reads are inline-asm ds_read_b128 + manual lgkmcnt(0) +
//    sched_barrier(0) (rule #18), so the compiler's LDS-DMA alias analysis
//    can't force a vmcnt drain before them.
//  - B regs double-buffered (bpA/bpB) via 2x-unrolled K loop (static indices
//    only — no scratch).
// ---------------------------------------------------------------------------
__device__ __forceinline__ bf16x8 unpack_b(int4 v)
{
    const uint32_t kMag = 0x43434343u;
    uint32_t p0 = __builtin_amdgcn_perm((uint32_t)v.y, (uint32_t)v.x, 0x0C0C0400u); // [b0,b1,0,0]
    uint32_t p1 = __builtin_amdgcn_perm((uint32_t)v.w, (uint32_t)v.z, 0x04000C0Cu); // [0,0,b2,b3]
    uint32_t bb = (p0 | p1) ^ 0x88888888u;          // nibbles n^8
    uint32_t lo = bb & 0x0F0F0F0Fu;                 // even-k weights
    uint32_t hi = (bb >> 4) & 0x0F0F0F0Fu;          // odd-k weights
    union { uint4 u; bf16x8 f; } o;
    o.u.x = __builtin_amdgcn_perm(kMag, lo, 0x04010400u);  // (k0,k2)+136
    o.u.y = __builtin_amdgcn_perm(kMag, lo, 0x04030402u);  // (k4,k6)+136
    o.u.z = __builtin_amdgcn_perm(kMag, hi, 0x04010400u);  // (k1,k3)+136
    o.u.w = __builtin_amdgcn_perm(kMag, hi, 0x04030402u);  // (k5,k7)+136
    return o.f;
}

// ds_read_b128 with literal byte offset (rule #18 pattern)
#define DSR(D, AD, OFF) \
    asm volatile("ds_read_b128 %0, %1 offset:" OFF : "=v"(D) : "v"(AD))

// One K=32 half-step: 8 A-fragment ds_reads (base + mi*2048), unpack 4 B
// fragments while reads are in flight, then lgkmcnt(0) + sched_barrier(0)
// and the 32-MFMA cluster.
#define PHASE(KH, AB, BPC)                                                  \
    {                                                                       \
        int4 afr[8];                                                        \
        const uint32_t ab_ = (AB);                                          \
        DSR(afr[0], ab_, "0");                                              \
        DSR(afr[1], ab_, "2048");                                           \
        DSR(afr[2], ab_, "4096");                                           \
        DSR(afr[3], ab_, "6144");                                           \
        DSR(afr[4], ab_, "8192");                                           \
        DSR(afr[5], ab_, "10240");                                          \
        DSR(afr[6], ab_, "12288");                                          \
        DSR(afr[7], ab_, "14336");                                          \
        bf16x8 bfr[4];                                                      \
        _Pragma("unroll")                                                   \
        for (int ni = 0; ni < 4; ++ni) bfr[ni] = unpack_b(BPC[KH][ni]);     \
        asm volatile("s_waitcnt lgkmcnt(0)" ::: "memory");                  \
        __builtin_amdgcn_sched_barrier(0);                                  \
        _Pragma("unroll")                                                   \
        for (int mi = 0; mi < 8; ++mi) {                                    \
            const bf16x8 afv = __builtin_bit_cast(bf16x8, afr[mi]);         \
            _Pragma("unroll")                                               \
            for (int ni = 0; ni < 4; ++ni)                                  \
                acc[mi][ni] = __builtin_amdgcn_mfma_f32_16x16x32_bf16(      \
                    afv, bfr[ni], acc[mi][ni], 0, 0, 0);                    \
        }                                                                   \
    }

// One K-step: prefetch A(tile KTN)->buf WBUF, compute tile from buf RBUF
// (B fragments BPC), prefetch B(tile KTN)->BPN between the two phases.
// Issue order matters for the counted waitcnt: 8 DMAs first, 8 B loads
// second -> vmcnt(8) at the end drains exactly the DMAs.
#define BODY(KTN, WBUF, RBUF, BPC, BPN)                                     \
    {                                                                       \
        _Pragma("unroll")                                                   \
        for (int i = 0; i < 8; ++i)                                         \
            __builtin_amdgcn_global_load_lds(                               \
                (const __attribute__((address_space(1))) void*)(            \
                    A + (size_t)gAbase + (size_t)i * 131072 + (size_t)(KTN) * BK), \
                (__attribute__((address_space(3))) void*)(                  \
                    sA + (WBUF) * 16384 + i * 2048 + ldsW), 16, 0, 0);      \
        asm volatile("" ::: "memory");                                      \
        PHASE(0, dsb0 + (RBUF) * 32768, BPC)                                \
        _Pragma("unroll")                                                   \
        for (int kh = 0; kh < 2; ++kh)                                      \
            _Pragma("unroll")                                               \
            for (int ni = 0; ni < 4; ++ni)                                  \
                BPN[kh][ni] = *(const int4*)(Bp + bOff[ni] + (KTN) * 32 + kh * 16); \
        PHASE(1, dsb1 + (RBUF) * 32768, BPC)                                \
        asm volatile("s_waitcnt vmcnt(8)" ::: "memory");                    \
        __builtin_amdgcn_s_barrier();                                       \
        asm volatile("" ::: "memory");                                      \
    }

__global__ __launch_bounds__(256, 2) void k_gemm(
    const bf16_t* __restrict__ A,     // xs [M][K] bf16 (k-permuted in 8-groups)
    const int* __restrict__ Bp,       // packed_w [N][K/2] int32 (low byte)
    const float* __restrict__ bias,
    const float* __restrict__ crow,
    float* __restrict__ out)
{
    __shared__ bf16_t sA[2 * 256 * BK];   // 64 KB double-buffered

    const int t = threadIdx.x;
    const int wave = t >> 6;
    const int lane = t & 63;
    const int fm = lane & 15;
    const int quad = lane >> 4;

    const int nBase = blockIdx.x * 128;
    const int mBase = blockIdx.y * 256;

    // A staging addressing (identical chunk layout to previous version,
    // algebraically folded: chunk c = i*256+t -> row = 32i + (t>>3), and the
    // rotated chunk index gc = ((t&7)+(t>>3))&7 is independent of i).
    const int gc = ((t & 7) + (t >> 3)) & 7;
    const uint32_t gAbase = (uint32_t)(mBase + (t >> 3)) * K_DIM + (uint32_t)(gc << 3);
    const int ldsW = wave * 512;          // element offset; + i*2048 + buf*16384

    const int wm = (wave >> 1) * 128;
    const int wn = (wave & 1) * 64;

    // B fragment row offsets (int32 units)
    int bOff[4];
#pragma unroll
    for (int ni = 0; ni < 4; ++ni)
        bOff[ni] = (nBase + wn + ni * 16 + fm) * (K_DIM / 2) + quad * 4;

    // ds_read byte bases. With the rotation swizzle, the physical chunk for
    // row r, logical chunk (kh*4+quad) is sc = ((kh*4+quad) - r) & 7; since
    // r = wm + mi*16 + fm and (wm + mi*16) % 8 == 0, sc is mi-independent:
    // addr = (wm+fm)*128 + (((kh*4+quad)-fm)&7)*16 + mi*2048 + buf*32768.
    const uint32_t sAb = (uint32_t)(size_t)(__attribute__((address_space(3))) bf16_t*)sA;
    const uint32_t dsb0 = sAb + (uint32_t)((wm + fm) * 128 + ((((0 + quad) - fm) & 7) << 4));
    const uint32_t dsb1 = sAb + (uint32_t)((wm + fm) * 128 + ((((4 + quad) - fm) & 7) << 4));

    floatx4 acc[8][4];
#pragma unroll
    for (int mi = 0; mi < 8; ++mi)
#pragma unroll
        for (int ni = 0; ni < 4; ++ni)
            acc[mi][ni] = (floatx4){0.f, 0.f, 0.f, 0.f};

    int4 bpA[2][4], bpB[2][4];

    // ---- prologue: stage A tile 0 into buf0, load B tile 0 into bpA ----
#pragma unroll
    for (int i = 0; i < 8; ++i)
        __builtin_amdgcn_global_load_lds(
            (const __attribute__((address_space(1))) void*)(
                A + (size_t)gAbase + (size_t)i * 131072),
            (__attribute__((address_space(3))) void*)(sA + i * 2048 + ldsW), 16, 0, 0);
    asm volatile("" ::: "memory");
#pragma unroll
    for (int kh = 0; kh < 2; ++kh)
#pragma unroll
        for (int ni = 0; ni < 4; ++ni)
            bpA[kh][ni] = *(const int4*)(Bp + bOff[ni] + kh * 16);
    asm volatile("s_waitcnt vmcnt(8)" ::: "memory");   // A DMAs done, B in flight
    __builtin_amdgcn_s_barrier();
    asm volatile("" ::: "memory");

    // ---- main loop, 2x unrolled for the register double-buffers ----
#pragma unroll 1
    for (int kt = 0; kt < NT; kt += 2) {
        const int k1 = kt + 1;
        const int k2 = (kt + 2) & (NT - 1);   // wraps to 0 on last iter (benign)
        BODY(k1, 1, 0, bpA, bpB)
        BODY(k2, 0, 1, bpB, bpA)
    }

    // epilogue: + bias[n] - crow[m]; C/D map: col=lane&15, row=quad*4+reg
    // nontemporal stores: keep the 180 MB out-stream from evicting Bp in LLC
#pragma unroll
    for (int mi = 0; mi < 8; ++mi) {
        const int m0 = mBase + wm + mi * 16 + quad * 4;
        float cr[4];
#pragma unroll
        for (int r = 0; r < 4; ++r) cr[r] = crow[m0 + r];
#pragma unroll
        for (int ni = 0; ni < 4; ++ni) {
            const int n = nBase + wn + ni * 16 + fm;
            const float bn = bias[n];
#pragma unroll
            for (int r = 0; r < 4; ++r)
                __builtin_nontemporal_store(acc[mi][ni][r] + bn - cr[r],
                                            &out[(size_t)(m0 + r) * N_DIM + n]);
        }
    }
}

// ---------------------------------------------------------------------------
extern "C" void kernel_launch(void* const* d_in, const int* in_sizes, int n_in,
                              void* d_out, int out_size, void* d_ws, size_t ws_size,
                              hipStream_t stream)
{
    const float* x      = (const float*)d_in[0];
    const int*   pw     = (const int*)d_in[1];
    const float* scales = (const float*)d_in[2];
    const float* zps    = (const float*)d_in[3];
    const float* bias   = (const float*)d_in[4];
    float* out = (float*)d_out;

    char* ws = (char*)d_ws;
    bf16_t* xs   = (bf16_t*)ws;               // 4096*4096*2 = 33554432 B
    float*  crow = (float*)(ws + 33554432);   // 4096*4      = 16384 B

    hipLaunchKernelGGL(k_prescale, dim3(M_DIM), dim3(256), 0, stream,
                       x, scales, zps, xs, crow);
    hipLaunchKernelGGL(k_gemm, dim3(N_DIM / 128, M_DIM / 256), dim3(256), 0, stream,
                       (const bf16_t*)xs, pw, bias, crow, out);
}

// Round 2
// 761.989 us; speedup vs baseline: 1.6755x; 1.6755x over previous
//
#include <hip/hip_runtime.h>
#include <hip/hip_bf16.h>
#include <stdint.h>

#define M_DIM 4096
#define K_DIM 4096
#define N_DIM 11008
#define BK 64
#define NT (K_DIM / BK)   // 64 K-steps

typedef __bf16 bf16_t;
typedef __bf16 bf16x8 __attribute__((ext_vector_type(8)));
typedef float floatx4 __attribute__((ext_vector_type(4)));

// ---------------------------------------------------------------------------
// k_prescale: xs[m, perm(k)] = bf16(x[m,k] * s[k/64]);
//             crow[m] = sum_k float(xs) * (zp[g] + 136)
// One WAVE per row (was: one 256-thread block per row): 16 independent
// float4 loads per lane for latency hiding, pure intra-wave shuffle reduce,
// no LDS, no __syncthreads. Output layout identical to previous version
// (k-permutation (0,2,4,6,1,3,5,7) within each aligned 8-group).
// ---------------------------------------------------------------------------
__global__ __launch_bounds__(256) void k_prescale(
    const float* __restrict__ x,
    const float* __restrict__ scales,
    const float* __restrict__ zps,
    bf16_t* __restrict__ xs,
    float* __restrict__ crow)
{
    const int wid  = (blockIdx.x << 2) | (threadIdx.x >> 6);  // wave id = row
    const int lane = threadIdx.x & 63;
    const float4* xr = (const float4*)(x + (size_t)wid * K_DIM);
    bf16x8* xo = (bf16x8*)(xs + (size_t)wid * K_DIM);
    float acc = 0.f;
#pragma unroll
    for (int j = 0; j < 8; ++j) {
        const int idx = j * 64 + lane;        // 8-elem group index (512/row)
        const int g = idx >> 3;               // 64 elems per quant group
        const float s = scales[g];
        const float tz = zps[g] + 136.0f;
        const float4 v0 = xr[2 * idx];
        const float4 v1 = xr[2 * idx + 1];
        bf16x8 o;
        o[0] = (bf16_t)(v0.x * s);  // k+0
        o[1] = (bf16_t)(v0.z * s);  // k+2
        o[2] = (bf16_t)(v1.x * s);  // k+4
        o[3] = (bf16_t)(v1.z * s);  // k+6
        o[4] = (bf16_t)(v0.y * s);  // k+1
        o[5] = (bf16_t)(v0.w * s);  // k+3
        o[6] = (bf16_t)(v1.y * s);  // k+5
        o[7] = (bf16_t)(v1.w * s);  // k+7
        xo[idx] = o;
        float ssum = 0.f;
#pragma unroll
        for (int jj = 0; jj < 8; ++jj) ssum += (float)o[jj];
        acc += ssum * tz;
    }
#pragma unroll
    for (int off = 32; off > 0; off >>= 1) acc += __shfl_down(acc, off, 64);
    if (lane == 0) crow[wid] = acc;
}

// ---------------------------------------------------------------------------
// k_gemm, fused int4 decode, B kept entirely in registers.
//   out[m,n] = sum_k xs[m,k]*(w4[n,k]+136) + bias[n] - crow[m]
// Block tile 256x128, BK=64, 4 waves in 2(m)x2(n): wave tile 128x64.
//
// T3 minimal 2-phase pipeline (register-lean rework of the round-1 attempt,
// which spilled: VGPR cap 128 w/ launch_bounds(256,2), acc eats 128 AGPR):
//   per iteration kt:
//     1. bfr = unpack(bp)          // bp loaded a FULL iteration ago -> the
//                                  // compiler's auto vmcnt(0) is stall-free
//     2. asm vmcnt(0); raw s_barrier; fence
//                                  // buf[kt&1] globally ready; buf[~kt&1]
//                                  // globally done being read
//     3. issue 8 DMAs  (A tile kt+1 -> buf[~kt&1])
//     4. issue 8 loads (B tile kt+1 -> bp)       // WAR on regs, in-order ok
//     5. sched_barrier(0)          // pin prefetch issue before MFMA region
//     6. MFMA phases on buf[kt&1] (plain per-mi ds_read, compiler lgkmcnt)
// One barrier/iter (was 2). All VMEM gets the whole MFMA block as cover.
// Registers: bp 32 + bfr 32 + addr ~25 + transients -> ~110 VGPR + 128 AGPR.
// ---------------------------------------------------------------------------
__device__ __forceinline__ bf16x8 unpack_b(int4 v)
{
    const uint32_t kMag = 0x43434343u;
    uint32_t p0 = __builtin_amdgcn_perm((uint32_t)v.y, (uint32_t)v.x, 0x0C0C0400u); // [b0,b1,0,0]
    uint32_t p1 = __builtin_amdgcn_perm((uint32_t)v.w, (uint32_t)v.z, 0x04000C0Cu); // [0,0,b2,b3]
    uint32_t bb = (p0 | p1) ^ 0x88888888u;          // nibbles n^8
    uint32_t lo = bb & 0x0F0F0F0Fu;                 // even-k weights
    uint32_t hi = (bb >> 4) & 0x0F0F0F0Fu;          // odd-k weights
    union { uint4 u; bf16x8 f; } o;
    o.u.x = __builtin_amdgcn_perm(kMag, lo, 0x04010400u);  // (k0,k2)+136
    o.u.y = __builtin_amdgcn_perm(kMag, lo, 0x04030402u);  // (k4,k6)+136
    o.u.z = __builtin_amdgcn_perm(kMag, hi, 0x04010400u);  // (k1,k3)+136
    o.u.w = __builtin_amdgcn_perm(kMag, hi, 0x04030402u);  // (k5,k7)+136
    return o.f;
}

__global__ __launch_bounds__(256, 2) void k_gemm(
    const bf16_t* __restrict__ A,     // xs [M][K] bf16 (k-permuted in 8-groups)
    const int* __restrict__ Bp,       // packed_w [N][K/2] int32 (low byte)
    const float* __restrict__ bias,
    const float* __restrict__ crow,
    float* __restrict__ out)
{
    __shared__ bf16_t sA[2 * 256 * BK];   // 64 KB double-buffered

    const int t = threadIdx.x;
    const int wave = t >> 6;
    const int lane = t & 63;
    const int fm = lane & 15;
    const int quad = lane >> 4;

    const int nBase = blockIdx.x * 128;
    const int mBase = blockIdx.y * 256;

    // A staging addressing: chunk c = i*256+t -> row = 32i + (t>>3); rotated
    // chunk index gc = ((t&7)+(t>>3))&7 is i-independent.
    const int gc = ((t & 7) + (t >> 3)) & 7;
    const uint32_t gAbase = (uint32_t)(mBase + (t >> 3)) * K_DIM + (uint32_t)(gc << 3);
    const int ldsW = wave * 512;          // element offset; + i*2048 (+ buf*16384)

    const int wm = (wave >> 1) * 128;
    const int wn = (wave & 1) * 64;

    // B fragment row offsets (int32 units)
    int bOff[4];
#pragma unroll
    for (int ni = 0; ni < 4; ++ni)
        bOff[ni] = (nBase + wn + ni * 16 + fm) * (K_DIM / 2) + quad * 4;

    // A-fragment LDS addressing. Rotation swizzle: physical chunk for row r,
    // logical chunk (kh*4+quad) is sc = ((kh*4+quad)-r)&7; r%8 == fm%8, and
    // (wm + mi*16) % 8 == 0 -> sc is mi-independent.
    const int rowbase = (wm + fm) * 64;               // elements
    const int scb0 = ((((0) + quad) - fm) & 7) * 8;   // kh=0 chunk offset
    const int scb1 = ((((4) + quad) - fm) & 7) * 8;   // kh=1 chunk offset

    floatx4 acc[8][4];
#pragma unroll
    for (int mi = 0; mi < 8; ++mi)
#pragma unroll
        for (int ni = 0; ni < 4; ++ni)
            acc[mi][ni] = (floatx4){0.f, 0.f, 0.f, 0.f};

    int4 bp[2][4];
    bf16x8 bfr[2][4];

    // ---- prologue: stage A tile 0 into buf0, load B tile 0 into bp ----
#pragma unroll
    for (int i = 0; i < 8; ++i)
        __builtin_amdgcn_global_load_lds(
            (const __attribute__((address_space(1))) void*)(
                A + (size_t)gAbase + (size_t)i * 131072),
            (__attribute__((address_space(3))) void*)(sA + i * 2048 + ldsW), 16, 0, 0);
    asm volatile("" ::: "memory");
#pragma unroll
    for (int kh = 0; kh < 2; ++kh)
#pragma unroll
        for (int ni = 0; ni < 4; ++ni)
            bp[kh][ni] = *(const int4*)(Bp + bOff[ni] + kh * 16);

    // ---- main loop ----
#pragma unroll 1
    for (int kt = 0; kt < NT; ++kt) {
        const bf16_t* sAr = sA + (kt & 1) * 16384;          // compute buffer
        bf16_t* sAw = (bf16_t*)sA + ((kt + 1) & 1) * 16384; // prefetch buffer
        const int ktn = (kt + 1) & (NT - 1);  // wraps to 0 on last iter (benign)

        // 1. unpack current B (compiler auto-waits bp: issued a full iter ago)
#pragma unroll
        for (int kh = 0; kh < 2; ++kh)
#pragma unroll
            for (int ni = 0; ni < 4; ++ni)
                bfr[kh][ni] = unpack_b(bp[kh][ni]);

        // 2. drain own DMAs before barrier (pinned), raw barrier (no compiler
        //    full-drain like __syncthreads would emit)
        asm volatile("s_waitcnt vmcnt(0)" ::: "memory");
        __builtin_amdgcn_s_barrier();
        asm volatile("" ::: "memory");

        // 3. prefetch next A tile into the other buffer
#pragma unroll
        for (int i = 0; i < 8; ++i)
            __builtin_amdgcn_global_load_lds(
                (const __attribute__((address_space(1))) void*)(
                    A + (size_t)gAbase + (size_t)i * 131072 + (size_t)ktn * BK),
                (__attribute__((address_space(3))) void*)(sAw + i * 2048 + ldsW), 16, 0, 0);

        // 4. prefetch next B tile into bp (regs; WAR after step-1 reads)
#pragma unroll
        for (int kh = 0; kh < 2; ++kh)
#pragma unroll
            for (int ni = 0; ni < 4; ++ni)
                bp[kh][ni] = *(const int4*)(Bp + bOff[ni] + ktn * 32 + kh * 16);

        // 5. pin the prefetch issue before the MFMA region
        __builtin_amdgcn_sched_barrier(0);

        // 6. MFMA phases: per-mi plain ds_read (register-lean), fine lgkmcnt
        //    by the compiler; all VMEM above stays in flight underneath.
#pragma unroll
        for (int kh = 0; kh < 2; ++kh) {
            const int scb = kh ? scb1 : scb0;
#pragma unroll
            for (int mi = 0; mi < 8; ++mi) {
                const bf16x8 af = *(const bf16x8*)(sAr + rowbase + scb + mi * 1024);
#pragma unroll
                for (int ni = 0; ni < 4; ++ni)
                    acc[mi][ni] = __builtin_amdgcn_mfma_f32_16x16x32_bf16(
                        af, bfr[kh][ni], acc[mi][ni], 0, 0, 0);
            }
        }
    }

    // epilogue: + bias[n] - crow[m]; C/D map: col=lane&15, row=quad*4+reg
    // nontemporal stores: keep the 180 MB out-stream from evicting Bp in LLC
#pragma unroll
    for (int mi = 0; mi < 8; ++mi) {
        const int m0 = mBase + wm + mi * 16 + quad * 4;
        float cr[4];
#pragma unroll
        for (int r = 0; r < 4; ++r) cr[r] = crow[m0 + r];
#pragma unroll
        for (int ni = 0; ni < 4; ++ni) {
            const int n = nBase + wn + ni * 16 + fm;
            const float bn = bias[n];
#pragma unroll
            for (int r = 0; r < 4; ++r)
                __builtin_nontemporal_store(acc[mi][ni][r] + bn - cr[r],
                                            &out[(size_t)(m0 + r) * N_DIM + n]);
        }
    }
}

// ---------------------------------------------------------------------------
extern "C" void kernel_launch(void* const* d_in, const int* in_sizes, int n_in,
                              void* d_out, int out_size, void* d_ws, size_t ws_size,
                              hipStream_t stream)
{
    const float* x      = (const float*)d_in[0];
    const int*   pw     = (const int*)d_in[1];
    const float* scales = (const float*)d_in[2];
    const float* zps    = (const float*)d_in[3];
    const float* bias   = (const float*)d_in[4];
    float* out = (float*)d_out;

    char* ws = (char*)d_ws;
    bf16_t* xs   = (bf16_t*)ws;               // 4096*4096*2 = 33554432 B
    float*  crow = (float*)(ws + 33554432);   // 4096*4      = 16384 B

    hipLaunchKernelGGL(k_prescale, dim3(M_DIM / 4), dim3(256), 0, stream,
                       x, scales, zps, xs, crow);
    hipLaunchKernelGGL(k_gemm, dim3(N_DIM / 128, M_DIM / 256), dim3(256), 0, stream,
                       (const bf16_t*)xs, pw, bias, crow, out);
}